// Round 1
// baseline (873.422 us; speedup 1.0000x reference)
//
#include <hip/hip_runtime.h>
#include <math.h>

#define NPOS 6400      // H*W
#define BATCH 4
#define CIN 64
#define DI 32          // inter
#define NCHUNK 8       // split-K chunks over columns
#define CHL 800        // columns per chunk (NCHUNK*CHL = NPOS)
#define KT 80          // column tile staged in LDS
#define LOG2E 1.44269504088896f

// ---------------- Kernel A: theta/phi/g projections ----------------
// writes thetaT, phiT, gT as [B][N][DI] row-major
__global__ __launch_bounds__(192) void prep_kernel(
    const float* __restrict__ x,
    const float* __restrict__ w_theta, const float* __restrict__ b_theta,
    const float* __restrict__ w_phi,   const float* __restrict__ b_phi,
    const float* __restrict__ w_g,     const float* __restrict__ b_g,
    float* __restrict__ thetaT, float* __restrict__ phiT, float* __restrict__ gT)
{
    __shared__ float xs[CIN * 64];       // [c][p], stride 64 (2-way bank alias = free)
    __shared__ float wsh[3 * DI * CIN];  // [m][o][c]

    const int t  = threadIdx.x;
    const int b  = blockIdx.y;
    const int p0 = blockIdx.x * 64;

    const float* Wsrc[3] = {w_theta, w_phi, w_g};
    for (int idx = t; idx < 3 * DI * CIN; idx += 192) {
        wsh[idx] = Wsrc[idx / (DI * CIN)][idx % (DI * CIN)];
    }
    const float* xb = x + (size_t)b * CIN * NPOS;
    for (int idx = t; idx < CIN * 64; idx += 192) {
        int c = idx >> 6, p = idx & 63;
        xs[idx] = xb[(size_t)c * NPOS + p0 + p];
    }
    __syncthreads();

    const int m = t >> 6;   // 0=theta 1=phi 2=g
    const int p = t & 63;
    const float* wm = &wsh[m * DI * CIN];
    const float* bias_src = (m == 0) ? b_theta : (m == 1 ? b_phi : b_g);

    float acc[DI];
    #pragma unroll
    for (int o = 0; o < DI; o++) acc[o] = 0.f;

    for (int c = 0; c < CIN; c += 4) {
        float xv0 = xs[(c + 0) * 64 + p];
        float xv1 = xs[(c + 1) * 64 + p];
        float xv2 = xs[(c + 2) * 64 + p];
        float xv3 = xs[(c + 3) * 64 + p];
        #pragma unroll
        for (int o = 0; o < DI; o++) {
            const float4 w4 = *(const float4*)&wm[o * CIN + c];
            acc[o] += w4.x * xv0 + w4.y * xv1 + w4.z * xv2 + w4.w * xv3;
        }
    }

    float* outp = (m == 0 ? thetaT : (m == 1 ? phiT : gT))
                  + ((size_t)b * NPOS + p0 + p) * DI;
    #pragma unroll
    for (int j = 0; j < 8; j++) {
        float4 v;
        v.x = acc[4 * j + 0] + bias_src[4 * j + 0];
        v.y = acc[4 * j + 1] + bias_src[4 * j + 1];
        v.z = acc[4 * j + 2] + bias_src[4 * j + 2];
        v.w = acc[4 * j + 3] + bias_src[4 * j + 3];
        *(float4*)(outp + 4 * j) = v;
    }
}

// ---------------- Kernel B: flash attention (split-K partials) ----------------
__global__ __launch_bounds__(256) void attn_kernel(
    const float* __restrict__ thetaT, const float* __restrict__ phiT,
    const float* __restrict__ gT,
    float* __restrict__ Opart, float* __restrict__ MLpart)
{
    __shared__ float kt[KT * DI];
    __shared__ float vt[KT * DI];

    const int tid = threadIdx.x;
    const int b   = blockIdx.y;
    const int h   = blockIdx.z;
    const int m   = blockIdx.x * 256 + tid;   // row (query position)

    float4 q[8];
    const float4* qsrc = (const float4*)(thetaT + ((size_t)b * NPOS + m) * DI);
    #pragma unroll
    for (int i = 0; i < 8; i++) q[i] = qsrc[i];

    float4 o4[8];
    #pragma unroll
    for (int i = 0; i < 8; i++) o4[i] = make_float4(0.f, 0.f, 0.f, 0.f);
    float mrun = -INFINITY, lrun = 0.f;

    const int k0 = h * CHL;
    const float4* ksrc = (const float4*)(phiT + ((size_t)b * NPOS + k0) * DI);
    const float4* vsrc = (const float4*)(gT   + ((size_t)b * NPOS + k0) * DI);
    float4* kt4 = (float4*)kt;
    float4* vt4 = (float4*)vt;
    const int nf4 = KT * DI / 4;   // 640

    for (int t0 = 0; t0 < CHL; t0 += KT) {
        #pragma unroll
        for (int i = 0; i < (2 * nf4) / 256; i++) {   // 5 iters
            int idx = tid + i * 256;
            if (idx < nf4) kt4[idx]       = ksrc[t0 * (DI / 4) + idx];
            else           vt4[idx - nf4] = vsrc[t0 * (DI / 4) + (idx - nf4)];
        }
        __syncthreads();

        for (int kk = 0; kk < KT; kk += 8) {
            float s[8];
            #pragma unroll
            for (int j = 0; j < 8; j++) {
                const float4* kc = (const float4*)&kt[(kk + j) * DI];
                float pa = 0.f, pb = 0.f, pc = 0.f, pd = 0.f;
                #pragma unroll
                for (int i = 0; i < 8; i++) {
                    float4 kv = kc[i];
                    pa += q[i].x * kv.x;
                    pb += q[i].y * kv.y;
                    pc += q[i].z * kv.z;
                    pd += q[i].w * kv.w;
                }
                s[j] = (pa + pb) + (pc + pd);
            }
            float cmax = s[0];
            #pragma unroll
            for (int j = 1; j < 8; j++) cmax = fmaxf(cmax, s[j]);
            float mnew = fmaxf(mrun, cmax);
            float corr = exp2f((mrun - mnew) * LOG2E);
            lrun *= corr;
            #pragma unroll
            for (int i = 0; i < 8; i++) {
                o4[i].x *= corr; o4[i].y *= corr; o4[i].z *= corr; o4[i].w *= corr;
            }
            #pragma unroll
            for (int j = 0; j < 8; j++) {
                float pj = exp2f((s[j] - mnew) * LOG2E);
                lrun += pj;
                const float4* vc = (const float4*)&vt[(kk + j) * DI];
                #pragma unroll
                for (int i = 0; i < 8; i++) {
                    float4 vv = vc[i];
                    o4[i].x += pj * vv.x; o4[i].y += pj * vv.y;
                    o4[i].z += pj * vv.z; o4[i].w += pj * vv.w;
                }
            }
            mrun = mnew;
        }
        __syncthreads();
    }

    float4* od = (float4*)(Opart + (((size_t)h * BATCH + b) * NPOS + m) * DI);
    #pragma unroll
    for (int i = 0; i < 8; i++) od[i] = o4[i];
    *(float2*)(MLpart + (((size_t)h * BATCH + b) * NPOS + m) * 2)
        = make_float2(mrun, lrun);
}

// ---------------- Kernel C: merge partials + out-proj + BN + residual ----------------
__global__ __launch_bounds__(256) void merge_kernel(
    const float* __restrict__ Opart, const float* __restrict__ MLpart,
    const float* __restrict__ x,
    const float* __restrict__ w_out, const float* __restrict__ b_out,
    const float* __restrict__ gamma, const float* __restrict__ beta,
    const float* __restrict__ mean,  const float* __restrict__ var,
    float* __restrict__ out)
{
    __shared__ float ws[CIN * DI];   // w_out[o][c] * inv[o]
    __shared__ float shift[CIN];

    const int tid = threadIdx.x;
    if (tid < CIN) {
        float inv = gamma[tid] * rsqrtf(var[tid] + 1e-4f);
        shift[tid] = (b_out[tid] - mean[tid]) * inv + beta[tid];
    }
    for (int idx = tid; idx < CIN * DI; idx += 256) {
        int o = idx / DI;
        float inv = gamma[o] * rsqrtf(var[o] + 1e-4f);
        ws[idx] = w_out[idx] * inv;
    }
    __syncthreads();

    const int gid = blockIdx.x * 256 + tid;   // row over B*N
    const int b = gid / NPOS;
    const int m = gid % NPOS;

    float mv[NCHUNK], lv[NCHUNK];
    float mM = -INFINITY;
    #pragma unroll
    for (int h = 0; h < NCHUNK; h++) {
        float2 ml = *(const float2*)(MLpart + (((size_t)h * BATCH + b) * NPOS + m) * 2);
        mv[h] = ml.x; lv[h] = ml.y;
        mM = fmaxf(mM, ml.x);
    }
    float L = 0.f;
    float y[DI];
    #pragma unroll
    for (int c = 0; c < DI; c++) y[c] = 0.f;
    #pragma unroll
    for (int h = 0; h < NCHUNK; h++) {
        float w = exp2f((mv[h] - mM) * LOG2E);
        L += lv[h] * w;
        const float4* op = (const float4*)(Opart + (((size_t)h * BATCH + b) * NPOS + m) * DI);
        #pragma unroll
        for (int i = 0; i < 8; i++) {
            float4 v = op[i];
            y[4 * i + 0] += w * v.x; y[4 * i + 1] += w * v.y;
            y[4 * i + 2] += w * v.z; y[4 * i + 3] += w * v.w;
        }
    }
    float rL = 1.f / L;
    #pragma unroll
    for (int c = 0; c < DI; c++) y[c] *= rL;

    const float* xb = x   + (size_t)b * CIN * NPOS + m;
    float*       ob = out + (size_t)b * CIN * NPOS + m;
    #pragma unroll
    for (int o = 0; o < CIN; o++) {
        const float* wrow = &ws[o * DI];
        float a0 = 0.f, a1 = 0.f, a2 = 0.f, a3 = 0.f;
        #pragma unroll
        for (int c = 0; c < DI; c += 4) {
            a0 += wrow[c + 0] * y[c + 0];
            a1 += wrow[c + 1] * y[c + 1];
            a2 += wrow[c + 2] * y[c + 2];
            a3 += wrow[c + 3] * y[c + 3];
        }
        ob[(size_t)o * NPOS] = (a0 + a1) + (a2 + a3) + shift[o] + xb[(size_t)o * NPOS];
    }
}

extern "C" void kernel_launch(void* const* d_in, const int* in_sizes, int n_in,
                              void* d_out, int out_size, void* d_ws, size_t ws_size,
                              hipStream_t stream) {
    (void)in_sizes; (void)n_in; (void)out_size; (void)ws_size;
    const float* x       = (const float*)d_in[0];
    const float* w_theta = (const float*)d_in[1];
    const float* b_theta = (const float*)d_in[2];
    const float* w_phi   = (const float*)d_in[3];
    const float* b_phi   = (const float*)d_in[4];
    const float* w_g     = (const float*)d_in[5];
    const float* b_g     = (const float*)d_in[6];
    const float* w_out   = (const float*)d_in[7];
    const float* b_out   = (const float*)d_in[8];
    const float* gamma   = (const float*)d_in[9];
    const float* beta    = (const float*)d_in[10];
    const float* mean    = (const float*)d_in[11];
    const float* var     = (const float*)d_in[12];

    float* ws     = (float*)d_ws;
    const size_t nbn = (size_t)BATCH * NPOS * DI;        // 819200
    float* thetaT = ws;
    float* phiT   = ws + nbn;
    float* gT     = ws + 2 * nbn;
    float* Opart  = ws + 3 * nbn;                        // NCHUNK*B*N*DI
    float* MLpart = Opart + (size_t)NCHUNK * BATCH * NPOS * DI;

    prep_kernel<<<dim3(NPOS / 64, BATCH), 192, 0, stream>>>(
        x, w_theta, b_theta, w_phi, b_phi, w_g, b_g, thetaT, phiT, gT);
    attn_kernel<<<dim3(NPOS / 256, BATCH, NCHUNK), 256, 0, stream>>>(
        thetaT, phiT, gT, Opart, MLpart);
    merge_kernel<<<dim3((BATCH * NPOS) / 256), 256, 0, stream>>>(
        Opart, MLpart, x, w_out, b_out, gamma, beta, mean, var, (float*)d_out);
}

// Round 2
// 221.731 us; speedup vs baseline: 3.9391x; 3.9391x over previous
//
#include <hip/hip_runtime.h>
#include <math.h>

#define NPOS 6400      // H*W
#define BATCH 4
#define CIN 64
#define DI 32          // inter
#define NCHUNK 4       // split over key columns
#define CHL 1600       // columns per chunk
#define KT 64          // column tile
#define NTILES (CHL / KT)   // 25
#define LOG2E 1.44269504088896f

typedef unsigned short u16;
typedef unsigned int   u32;
typedef __attribute__((ext_vector_type(8))) short short8;
typedef __attribute__((ext_vector_type(4))) float f4v;

__device__ __forceinline__ u32 bfb(float f) {
    // fp32 -> bf16 bits, round-half-up
    return (__float_as_uint(f) + 0x8000u) >> 16;
}

// ---------------- Kernel A: projections -> bf16 thetaT/phiT (row-major [B][N][32]),
// gTt transposed ([B][32][N]) ----------------
__global__ __launch_bounds__(192) void prep_kernel(
    const float* __restrict__ x,
    const float* __restrict__ w_theta, const float* __restrict__ b_theta,
    const float* __restrict__ w_phi,   const float* __restrict__ b_phi,
    const float* __restrict__ w_g,     const float* __restrict__ b_g,
    u16* __restrict__ thetaT, u16* __restrict__ phiT, u16* __restrict__ gTt)
{
    __shared__ float xs[CIN * 64];       // [c][p]
    __shared__ float wsh[3 * DI * CIN];  // [m][o][c]

    const int t  = threadIdx.x;
    const int b  = blockIdx.y;
    const int p0 = blockIdx.x * 64;

    const float* Wsrc[3] = {w_theta, w_phi, w_g};
    for (int idx = t; idx < 3 * DI * CIN; idx += 192)
        wsh[idx] = Wsrc[idx / (DI * CIN)][idx % (DI * CIN)];
    const float* xb = x + (size_t)b * CIN * NPOS;
    for (int idx = t; idx < CIN * 64; idx += 192) {
        int c = idx >> 6, p = idx & 63;
        xs[idx] = xb[(size_t)c * NPOS + p0 + p];
    }
    __syncthreads();

    const int m = t >> 6;   // 0=theta 1=phi 2=g
    const int p = t & 63;
    const float* wm = &wsh[m * DI * CIN];
    const float* bias_src = (m == 0) ? b_theta : (m == 1 ? b_phi : b_g);

    float acc[DI];
    #pragma unroll
    for (int o = 0; o < DI; o++) acc[o] = 0.f;

    for (int c = 0; c < CIN; c += 4) {
        float xv0 = xs[(c + 0) * 64 + p];
        float xv1 = xs[(c + 1) * 64 + p];
        float xv2 = xs[(c + 2) * 64 + p];
        float xv3 = xs[(c + 3) * 64 + p];
        #pragma unroll
        for (int o = 0; o < DI; o++) {
            const float4 w4 = *(const float4*)&wm[o * CIN + c];
            acc[o] += w4.x * xv0 + w4.y * xv1 + w4.z * xv2 + w4.w * xv3;
        }
    }
    #pragma unroll
    for (int o = 0; o < DI; o++) acc[o] += bias_src[o];

    if (m == 2) {
        // g: transposed scatter, coalesced across p per output channel
        #pragma unroll
        for (int o = 0; o < DI; o++)
            gTt[((size_t)b * DI + o) * NPOS + p0 + p] = (u16)bfb(acc[o]);
    } else {
        u16* dst = (m == 0 ? thetaT : phiT) + ((size_t)b * NPOS + p0 + p) * DI;
        const float sc = (m == 0) ? LOG2E : 1.0f;   // fold log2(e) into Q
        u32 wbuf[16];
        #pragma unroll
        for (int j = 0; j < 16; j++) {
            u32 lo = bfb(acc[2 * j] * sc);
            u32 hi = bfb(acc[2 * j + 1] * sc);
            wbuf[j] = lo | (hi << 16);
        }
        u32* d32 = (u32*)dst;
        #pragma unroll
        for (int j = 0; j < 4; j++)
            *(uint4*)(d32 + 4 * j) = make_uint4(wbuf[4*j], wbuf[4*j+1], wbuf[4*j+2], wbuf[4*j+3]);
    }
}

// ---------------- Kernel B: MFMA flash attention ----------------
// Wave handles 32 query rows (two 16-row m-tiles). S^T = K·Q^T via
// mfma_16x16x32_bf16 (C-layout col = query m = lane&15 -> softmax state per
// lane column). PV as O^T = V^T·P^T; P round-trips through per-wave-private
// LDS (no barriers in this kernel).
__global__ __launch_bounds__(256) void attn_kernel(
    const u16* __restrict__ thetaT, const u16* __restrict__ phiT,
    const u16* __restrict__ gTt,
    float* __restrict__ Ypart, float* __restrict__ MLpart)
{
    __shared__ u32 plds_all[4][17 * 32];   // per-wave private P buffer (pad stride 17)
    const int tid  = threadIdx.x;
    const int wid  = tid >> 6;
    const int lane = tid & 63;
    const int g    = lane >> 4;   // k-chunk / row-group
    const int mq   = lane & 15;
    u32* plds = plds_all[wid];

    const int b     = blockIdx.y;
    const int cc    = blockIdx.z;
    const int mbase = blockIdx.x * 128 + wid * 32;
    const int c0    = cc * CHL;

    // Q^T B-frags: lane -> query row mbase+mt*16+mq, k-chunk g*8  (bf16, 16B)
    short8 qf[2];
    #pragma unroll
    for (int mt = 0; mt < 2; mt++)
        qf[mt] = *(const short8*)(thetaT + ((size_t)b * NPOS + mbase + mt * 16 + mq) * DI + g * 8);

    f4v o[2][2];
    #pragma unroll
    for (int mt = 0; mt < 2; mt++)
        #pragma unroll
        for (int h = 0; h < 2; h++)
            o[mt][h] = (f4v){0.f, 0.f, 0.f, 0.f};
    float mrun[2] = {-INFINITY, -INFINITY};
    float lrun[2] = {0.f, 0.f};

    for (int t = 0; t < NTILES; t++) {
        const int n0 = c0 + t * KT;

        // K A-frags: row n0+nf*16+mq, k-chunk g*8 (contiguous 16B, L2-resident)
        short8 kf[4];
        #pragma unroll
        for (int nf = 0; nf < 4; nf++)
            kf[nf] = *(const short8*)(phiT + ((size_t)b * NPOS + n0 + nf * 16 + mq) * DI + g * 8);
        // V^T A-frags: row d = h*16+mq of gTt, n-chunk kc*32+g*8
        short8 vf[2][2];
        #pragma unroll
        for (int h = 0; h < 2; h++)
            #pragma unroll
            for (int kc = 0; kc < 2; kc++)
                vf[h][kc] = *(const short8*)(gTt + ((size_t)b * DI + h * 16 + mq) * NPOS + n0 + kc * 32 + g * 8);

        #pragma unroll
        for (int mt = 0; mt < 2; mt++) {
            // S^T tile: rows n (local 4g+r per frag nf), col m = mq. Already log2-scaled.
            f4v s4[4];
            #pragma unroll
            for (int nf = 0; nf < 4; nf++)
                s4[nf] = __builtin_amdgcn_mfma_f32_16x16x32_bf16(
                    kf[nf], qf[mt], (f4v){0.f, 0.f, 0.f, 0.f}, 0, 0, 0);

            // row (query) max over 64 cols: in-lane 16, then lanes m,m+16,m+32,m+48
            float mx = s4[0][0];
            #pragma unroll
            for (int nf = 0; nf < 4; nf++)
                #pragma unroll
                for (int r = 0; r < 4; r++)
                    mx = fmaxf(mx, s4[nf][r]);
            mx = fmaxf(mx, __shfl_xor(mx, 16));
            mx = fmaxf(mx, __shfl_xor(mx, 32));

            float mnew = fmaxf(mrun[mt], mx);
            float corr = exp2f(mrun[mt] - mnew);

            float p[16];
            float sum = 0.f;
            #pragma unroll
            for (int nf = 0; nf < 4; nf++)
                #pragma unroll
                for (int r = 0; r < 4; r++) {
                    float pv = exp2f(s4[nf][r] - mnew);
                    p[nf * 4 + r] = pv;
                    sum += pv;
                }
            sum += __shfl_xor(sum, 16);
            sum += __shfl_xor(sum, 32);
            lrun[mt] = lrun[mt] * corr + sum;
            mrun[mt] = mnew;
            #pragma unroll
            for (int h = 0; h < 2; h++)
                #pragma unroll
                for (int r = 0; r < 4; r++)
                    o[mt][h][r] *= corr;

            // P^T -> LDS as bf16 pairs along n: np = (nf*16+4g+r)>>1 = 8nf+2g+(r>>1)
            #pragma unroll
            for (int nf = 0; nf < 4; nf++)
                #pragma unroll
                for (int q = 0; q < 2; q++)
                    plds[(8 * nf + 2 * g + q) * 17 + mq] =
                        (bfb(p[nf * 4 + 2 * q + 1]) << 16) | bfb(p[nf * 4 + 2 * q]);

            __builtin_amdgcn_s_waitcnt(0xC07F);   // lgkmcnt(0) only

            // P^T B-frags (k = n = kc*32 + g*8 + j) and PV MFMAs
            #pragma unroll
            for (int kc = 0; kc < 2; kc++) {
                union { u32 u[4]; short8 s; } pf;
                #pragma unroll
                for (int jp = 0; jp < 4; jp++)
                    pf.u[jp] = plds[(kc * 16 + 4 * g + jp) * 17 + mq];
                #pragma unroll
                for (int h = 0; h < 2; h++)
                    o[mt][h] = __builtin_amdgcn_mfma_f32_16x16x32_bf16(
                        vf[h][kc], pf.s, o[mt][h], 0, 0, 0);
            }
        }
    }

    // epilogue: O^T C-layout col = m = mq, row d = h*16 + 4g + r
    #pragma unroll
    for (int mt = 0; mt < 2; mt++) {
        float rl = 1.f / lrun[mt];
        size_t rowb = (size_t)(cc * BATCH + b) * NPOS + mbase + mt * 16 + mq;
        float* yp = Ypart + rowb * DI;
        #pragma unroll
        for (int h = 0; h < 2; h++) {
            *(float2*)(yp + h * 16 + 4 * g)     = make_float2(o[mt][h][0] * rl, o[mt][h][1] * rl);
            *(float2*)(yp + h * 16 + 4 * g + 2) = make_float2(o[mt][h][2] * rl, o[mt][h][3] * rl);
        }
        if (g == 0)
            *(float2*)(MLpart + rowb * 2) = make_float2(mrun[mt], lrun[mt]);
    }
}

// ---------------- Kernel C: merge chunks (base-2 LSE) + out-proj + BN + residual ----------------
__global__ __launch_bounds__(256) void merge_kernel(
    const float* __restrict__ Ypart, const float* __restrict__ MLpart,
    const float* __restrict__ x,
    const float* __restrict__ w_out, const float* __restrict__ b_out,
    const float* __restrict__ gamma, const float* __restrict__ beta,
    const float* __restrict__ mean,  const float* __restrict__ var,
    float* __restrict__ out)
{
    __shared__ float ws[CIN * DI];   // w_out[o][c] * inv[o]
    __shared__ float shift[CIN];

    const int tid = threadIdx.x;
    if (tid < CIN) {
        float inv = gamma[tid] * rsqrtf(var[tid] + 1e-4f);
        shift[tid] = (b_out[tid] - mean[tid]) * inv + beta[tid];
    }
    for (int idx = tid; idx < CIN * DI; idx += 256) {
        int o = idx / DI;
        float inv = gamma[o] * rsqrtf(var[o] + 1e-4f);
        ws[idx] = w_out[idx] * inv;
    }
    __syncthreads();

    const int gid = blockIdx.x * 256 + tid;   // row over B*N
    const int b = gid / NPOS;
    const int m = gid % NPOS;

    float mv[NCHUNK], lv[NCHUNK];
    float mM = -INFINITY;
    #pragma unroll
    for (int h = 0; h < NCHUNK; h++) {
        float2 ml = *(const float2*)(MLpart + ((size_t)(h * BATCH + b) * NPOS + m) * 2);
        mv[h] = ml.x; lv[h] = ml.y;
        mM = fmaxf(mM, ml.x);
    }
    float L = 0.f;
    float y[DI];
    #pragma unroll
    for (int c = 0; c < DI; c++) y[c] = 0.f;
    #pragma unroll
    for (int h = 0; h < NCHUNK; h++) {
        float w = exp2f(mv[h] - mM) * lv[h];   // base-2 domain (theta pre-scaled)
        L += w;
        const float4* op = (const float4*)(Ypart + ((size_t)(h * BATCH + b) * NPOS + m) * DI);
        float wl = exp2f(mv[h] - mM) * lv[h];
        (void)wl;
        float wn = exp2f(mv[h] - mM) * lv[h] / lv[h];   // = exp2(mv-mM)
        #pragma unroll
        for (int i = 0; i < 8; i++) {
            float4 v = op[i];
            // Ypart rows are already normalized by their own l; weight = w_h = 2^(m_h-M)*l_h
            float wq = exp2f(mv[h] - mM) * lv[h];
            y[4 * i + 0] += wq * v.x; y[4 * i + 1] += wq * v.y;
            y[4 * i + 2] += wq * v.z; y[4 * i + 3] += wq * v.w;
        }
        (void)wn;
    }
    float rL = 1.f / L;
    #pragma unroll
    for (int c = 0; c < DI; c++) y[c] *= rL;

    const float* xb = x   + (size_t)b * CIN * NPOS + m;
    float*       ob = out + (size_t)b * CIN * NPOS + m;
    #pragma unroll
    for (int o = 0; o < CIN; o++) {
        const float* wrow = &ws[o * DI];
        float a0 = 0.f, a1 = 0.f, a2 = 0.f, a3 = 0.f;
        #pragma unroll
        for (int c = 0; c < DI; c += 4) {
            a0 += wrow[c + 0] * y[c + 0];
            a1 += wrow[c + 1] * y[c + 1];
            a2 += wrow[c + 2] * y[c + 2];
            a3 += wrow[c + 3] * y[c + 3];
        }
        ob[(size_t)o * NPOS] = (a0 + a1) + (a2 + a3) + shift[o] + xb[(size_t)o * NPOS];
    }
}

extern "C" void kernel_launch(void* const* d_in, const int* in_sizes, int n_in,
                              void* d_out, int out_size, void* d_ws, size_t ws_size,
                              hipStream_t stream) {
    (void)in_sizes; (void)n_in; (void)out_size; (void)ws_size;
    const float* x       = (const float*)d_in[0];
    const float* w_theta = (const float*)d_in[1];
    const float* b_theta = (const float*)d_in[2];
    const float* w_phi   = (const float*)d_in[3];
    const float* b_phi   = (const float*)d_in[4];
    const float* w_g     = (const float*)d_in[5];
    const float* b_g     = (const float*)d_in[6];
    const float* w_out   = (const float*)d_in[7];
    const float* b_out   = (const float*)d_in[8];
    const float* gamma   = (const float*)d_in[9];
    const float* beta    = (const float*)d_in[10];
    const float* mean    = (const float*)d_in[11];
    const float* var     = (const float*)d_in[12];

    float* ws = (float*)d_ws;
    const size_t YN  = (size_t)NCHUNK * BATCH * NPOS * DI;   // 3,276,800 floats
    const size_t MLN = (size_t)NCHUNK * BATCH * NPOS * 2;    //   204,800 floats
    float* Ypart  = ws;
    float* MLpart = ws + YN;
    u16* thetaT = (u16*)(ws + YN + MLN);
    u16* phiT   = thetaT + (size_t)BATCH * NPOS * DI;
    u16* gTt    = phiT   + (size_t)BATCH * NPOS * DI;

    prep_kernel<<<dim3(NPOS / 64, BATCH), 192, 0, stream>>>(
        x, w_theta, b_theta, w_phi, b_phi, w_g, b_g, thetaT, phiT, gTt);
    attn_kernel<<<dim3(NPOS / 128, BATCH, NCHUNK), 256, 0, stream>>>(
        thetaT, phiT, gTt, Ypart, MLpart);
    merge_kernel<<<dim3((BATCH * NPOS) / 256), 256, 0, stream>>>(
        Ypart, MLpart, x, w_out, b_out, gamma, beta, mean, var, (float*)d_out);
}

// Round 3
// 172.858 us; speedup vs baseline: 5.0528x; 1.2827x over previous
//
#include <hip/hip_runtime.h>
#include <math.h>

#define NPOS 6400      // H*W
#define BATCH 4
#define CIN 64
#define DI 32          // inter
#define NCHUNK 5       // split over key columns
#define CHL (NPOS / NCHUNK)   // 1280
#define KT 64
#define NTILES (CHL / KT)     // 20
#define LOG2E 1.44269504088896f

typedef unsigned short u16;
typedef unsigned int   u32;
typedef __attribute__((ext_vector_type(8))) short short8;
typedef __attribute__((ext_vector_type(4))) float f4v;

__device__ __forceinline__ u32 bfb(float f) {
    return (__float_as_uint(f) + 0x8000u) >> 16;   // bf16 bits, round-half-up
}
__device__ __forceinline__ float fast_exp2(float x) {
    float r;
    asm("v_exp_f32 %0, %1" : "=v"(r) : "v"(x));
    return r;
}

// ---------------- Kernel A: projections ----------------
// thetaT/phiT row-major bf16 [B][N][32] (theta pre-scaled by log2e);
// gTt transposed bf16 [B][32][N]. Weights stay wave-uniform -> s_loads.
__global__ __launch_bounds__(256) void prep_kernel(
    const float* __restrict__ x,
    const float* __restrict__ w_theta, const float* __restrict__ b_theta,
    const float* __restrict__ w_phi,   const float* __restrict__ b_phi,
    const float* __restrict__ w_g,     const float* __restrict__ b_g,
    u16* __restrict__ thetaT, u16* __restrict__ phiT, u16* __restrict__ gTt)
{
    const int t    = threadIdx.x;
    const int b    = blockIdx.y;
    const int mgrp = blockIdx.z;
    const int p    = blockIdx.x * 256 + t;

    const float* wm; const float* bs;
    if (mgrp == 0)      { wm = w_theta; bs = b_theta; }
    else if (mgrp == 1) { wm = w_phi;   bs = b_phi;   }
    else                { wm = w_g;     bs = b_g;     }

    const float* xb = x + (size_t)b * CIN * NPOS + p;
    float xr[CIN];
    #pragma unroll
    for (int c = 0; c < CIN; c++) xr[c] = xb[(size_t)c * NPOS];

    float acc[DI];
    #pragma unroll
    for (int o = 0; o < DI; o++) acc[o] = bs[o];

    for (int cb = 0; cb < CIN; cb += 4) {
        #pragma unroll
        for (int o = 0; o < DI; o++) {
            float4 w4 = *(const float4*)&wm[o * CIN + cb];   // uniform -> s_load
            acc[o] += w4.x * xr[cb] + w4.y * xr[cb + 1]
                    + w4.z * xr[cb + 2] + w4.w * xr[cb + 3];
        }
    }

    if (mgrp == 2) {
        #pragma unroll
        for (int o = 0; o < DI; o++)
            gTt[((size_t)b * DI + o) * NPOS + p] = (u16)bfb(acc[o]);
    } else {
        u16* dst = (mgrp == 0 ? thetaT : phiT) + ((size_t)b * NPOS + p) * DI;
        const float sc = (mgrp == 0) ? LOG2E : 1.0f;
        u32 wb[16];
        #pragma unroll
        for (int j = 0; j < 16; j++)
            wb[j] = bfb(acc[2 * j] * sc) | (bfb(acc[2 * j + 1] * sc) << 16);
        u32* d32 = (u32*)dst;
        #pragma unroll
        for (int j = 0; j < 4; j++)
            *(uint4*)(d32 + 4 * j) =
                make_uint4(wb[4 * j], wb[4 * j + 1], wb[4 * j + 2], wb[4 * j + 3]);
    }
}

// ---------------- Kernel B: MFMA flash attention, no-max softmax ----------------
// Wave = 64 query rows (4 m-tiles). S^T = K.Q^T; p = exp2(s) raw (fp32 range
// absorbs the unnormalized scale); l via ones-MFMA; O^T = V^T.P^T with P
// round-tripped through XOR-swizzled per-wave LDS. No barriers.
__global__ __launch_bounds__(256) void attn_kernel(
    const u16* __restrict__ thetaT, const u16* __restrict__ phiT,
    const u16* __restrict__ gTt,
    float* __restrict__ Ypart, float* __restrict__ Lpart)
{
    __shared__ u32 plds_all[4][32 * 32];
    const int tid  = threadIdx.x;
    const int wid  = tid >> 6;
    const int lane = tid & 63;
    const int g    = lane >> 4;
    const int mq   = lane & 15;
    u32* plds = plds_all[wid];

    const int b     = blockIdx.y;
    const int cc    = blockIdx.z;
    const int mbase = blockIdx.x * 256 + wid * 64;
    const int c0    = cc * CHL;

    // XOR-swizzled LDS bases: word = row*32 + (mq ^ (swz(row)<<4)),
    // swz(row) = ((row>>1)^(row>>2))&1.  Write rows 8nf+2g+q -> swz = (g^(g>>1))&1;
    // read rows 16kc+4g+jp -> swz = ((jp>>1)^g)&1.  Both 2-way (free).
    const int swb_w = (g ^ (g >> 1)) & 1;
    u32* wp  = plds + 2 * g * 32 + (mq ^ (swb_w << 4));
    u32* rp0 = plds + 4 * g * 32 + (mq ^ ((g & 1) << 4));          // jp 0,1
    u32* rp1 = plds + 4 * g * 32 + (mq ^ (((g & 1) ^ 1) << 4));    // jp 2,3

    short8 qf[4];
    #pragma unroll
    for (int mt = 0; mt < 4; mt++)
        qf[mt] = *(const short8*)(thetaT + ((size_t)b * NPOS + mbase + mt * 16 + mq) * DI + g * 8);

    f4v o[4][2];
    f4v ll[4];
    #pragma unroll
    for (int mt = 0; mt < 4; mt++) {
        o[mt][0] = (f4v){0.f, 0.f, 0.f, 0.f};
        o[mt][1] = (f4v){0.f, 0.f, 0.f, 0.f};
        ll[mt]   = (f4v){0.f, 0.f, 0.f, 0.f};
    }
    const short8 ones = (short8)(short)0x3F80;   // bf16 1.0 broadcast

    const u16* kbase = phiT + (size_t)b * NPOS * DI;
    const u16* vbase = gTt  + (size_t)b * DI * NPOS;

    // register-double-buffered K/V tile loads
    short8 kf[4], vf[2][2], kn[4], vn[2][2];
    {
        const int n0 = c0;
        #pragma unroll
        for (int nf = 0; nf < 4; nf++)
            kf[nf] = *(const short8*)(kbase + (size_t)(n0 + nf * 16 + mq) * DI + g * 8);
        #pragma unroll
        for (int h = 0; h < 2; h++)
            #pragma unroll
            for (int kc = 0; kc < 2; kc++)
                vf[h][kc] = *(const short8*)(vbase + (size_t)(h * 16 + mq) * NPOS + n0 + kc * 32 + g * 8);
    }

    for (int t = 0; t < NTILES; t++) {
        const int tn = (t + 1 == NTILES) ? 0 : (t + 1);
        const int n1 = c0 + tn * KT;
        #pragma unroll
        for (int nf = 0; nf < 4; nf++)
            kn[nf] = *(const short8*)(kbase + (size_t)(n1 + nf * 16 + mq) * DI + g * 8);
        #pragma unroll
        for (int h = 0; h < 2; h++)
            #pragma unroll
            for (int kc = 0; kc < 2; kc++)
                vn[h][kc] = *(const short8*)(vbase + (size_t)(h * 16 + mq) * NPOS + n1 + kc * 32 + g * 8);

        #pragma unroll
        for (int mt = 0; mt < 4; mt++) {
            f4v s4[4];
            #pragma unroll
            for (int nf = 0; nf < 4; nf++)
                s4[nf] = __builtin_amdgcn_mfma_f32_16x16x32_bf16(
                    kf[nf], qf[mt], (f4v){0.f, 0.f, 0.f, 0.f}, 0, 0, 0);

            // p = exp2(s) raw; pack pairs (round-half-up) -> swizzled LDS
            #pragma unroll
            for (int nf = 0; nf < 4; nf++) {
                u32 e[4];
                #pragma unroll
                for (int r = 0; r < 4; r++)
                    e[r] = __float_as_uint(fast_exp2(s4[nf][r])) + 0x8000u;
                wp[(8 * nf + 0) * 32] = __builtin_amdgcn_perm(e[1], e[0], 0x07060302);
                wp[(8 * nf + 1) * 32] = __builtin_amdgcn_perm(e[3], e[2], 0x07060302);
            }

            // P^T B-frags from LDS (per-wave DS ops are in-order; compiler
            // inserts lgkmcnt before MFMA use) and PV + l MFMAs
            #pragma unroll
            for (int kc = 0; kc < 2; kc++) {
                union { u32 u[4]; short8 s; } pf;
                pf.u[0] = rp0[(kc * 16 + 0) * 32];
                pf.u[1] = rp0[(kc * 16 + 1) * 32];
                pf.u[2] = rp1[(kc * 16 + 2) * 32];
                pf.u[3] = rp1[(kc * 16 + 3) * 32];
                o[mt][0] = __builtin_amdgcn_mfma_f32_16x16x32_bf16(vf[0][kc], pf.s, o[mt][0], 0, 0, 0);
                o[mt][1] = __builtin_amdgcn_mfma_f32_16x16x32_bf16(vf[1][kc], pf.s, o[mt][1], 0, 0, 0);
                ll[mt]   = __builtin_amdgcn_mfma_f32_16x16x32_bf16(ones,      pf.s, ll[mt],   0, 0, 0);
            }
        }

        #pragma unroll
        for (int nf = 0; nf < 4; nf++) kf[nf] = kn[nf];
        #pragma unroll
        for (int h = 0; h < 2; h++) {
            vf[h][0] = vn[h][0];
            vf[h][1] = vn[h][1];
        }
    }

    // epilogue: raw (unnormalized) O^T + l partials
    #pragma unroll
    for (int mt = 0; mt < 4; mt++) {
        size_t rowb = (size_t)(cc * BATCH + b) * NPOS + mbase + mt * 16 + mq;
        float* yp = Ypart + rowb * DI;
        *(f4v*)(yp + 4 * g)      = o[mt][0];
        *(f4v*)(yp + 16 + 4 * g) = o[mt][1];
        if (g == 0) Lpart[rowb] = ll[mt][0];
    }
}

// ---------------- Kernel C: sum partials + out-proj + BN + residual ----------------
__global__ __launch_bounds__(256) void merge_kernel(
    const float* __restrict__ Ypart, const float* __restrict__ Lpart,
    const float* __restrict__ x,
    const float* __restrict__ w_out, const float* __restrict__ b_out,
    const float* __restrict__ gamma, const float* __restrict__ beta,
    const float* __restrict__ mean,  const float* __restrict__ var,
    float* __restrict__ out)
{
    __shared__ float wsm[CIN * DI];
    __shared__ float shift[CIN];

    const int tid = threadIdx.x;
    if (tid < CIN) {
        float inv = gamma[tid] * rsqrtf(var[tid] + 1e-4f);
        shift[tid] = (b_out[tid] - mean[tid]) * inv + beta[tid];
    }
    for (int idx = tid; idx < CIN * DI; idx += 256) {
        int o = idx / DI;
        wsm[idx] = w_out[idx] * (gamma[o] * rsqrtf(var[o] + 1e-4f));
    }
    __syncthreads();

    const int oq  = tid >> 6;          // wave = one o-quarter, 64 consecutive rows
    const int r   = tid & 63;
    const int row = blockIdx.x * 64 + r;
    const int b   = row / NPOS;
    const int m   = row - b * NPOS;

    float l = 0.f;
    float y[DI];
    #pragma unroll
    for (int c = 0; c < DI; c++) y[c] = 0.f;
    #pragma unroll
    for (int h = 0; h < NCHUNK; h++) {
        l += Lpart[((size_t)h * BATCH + b) * NPOS + m];
        const f4v* op = (const f4v*)(Ypart + (((size_t)h * BATCH + b) * NPOS + m) * DI);
        #pragma unroll
        for (int i = 0; i < 8; i++) {
            f4v v = op[i];
            y[4 * i + 0] += v[0]; y[4 * i + 1] += v[1];
            y[4 * i + 2] += v[2]; y[4 * i + 3] += v[3];
        }
    }
    float rl = 1.f / l;
    #pragma unroll
    for (int c = 0; c < DI; c++) y[c] *= rl;

    const float* xb = x   + (size_t)b * CIN * NPOS + m;
    float*       ob = out + (size_t)b * CIN * NPOS + m;
    #pragma unroll
    for (int i = 0; i < 16; i++) {
        int o = oq * 16 + i;
        const float* wr = &wsm[o * DI];
        float a0 = 0.f, a1 = 0.f, a2 = 0.f, a3 = 0.f;
        #pragma unroll
        for (int c = 0; c < DI; c += 4) {
            a0 += wr[c + 0] * y[c + 0];
            a1 += wr[c + 1] * y[c + 1];
            a2 += wr[c + 2] * y[c + 2];
            a3 += wr[c + 3] * y[c + 3];
        }
        ob[(size_t)o * NPOS] = (a0 + a1) + (a2 + a3) + shift[o] + xb[(size_t)o * NPOS];
    }
}

extern "C" void kernel_launch(void* const* d_in, const int* in_sizes, int n_in,
                              void* d_out, int out_size, void* d_ws, size_t ws_size,
                              hipStream_t stream) {
    (void)in_sizes; (void)n_in; (void)out_size; (void)ws_size;
    const float* x       = (const float*)d_in[0];
    const float* w_theta = (const float*)d_in[1];
    const float* b_theta = (const float*)d_in[2];
    const float* w_phi   = (const float*)d_in[3];
    const float* b_phi   = (const float*)d_in[4];
    const float* w_g     = (const float*)d_in[5];
    const float* b_g     = (const float*)d_in[6];
    const float* w_out   = (const float*)d_in[7];
    const float* b_out   = (const float*)d_in[8];
    const float* gamma   = (const float*)d_in[9];
    const float* beta    = (const float*)d_in[10];
    const float* mean    = (const float*)d_in[11];
    const float* var     = (const float*)d_in[12];

    float* ws = (float*)d_ws;
    const size_t YN  = (size_t)NCHUNK * BATCH * NPOS * DI;   // 4,096,000 floats
    const size_t LN  = (size_t)NCHUNK * BATCH * NPOS;        //   128,000 floats
    float* Ypart = ws;
    float* Lpart = ws + YN;
    u16* thetaT = (u16*)(ws + YN + LN);
    u16* phiT   = thetaT + (size_t)BATCH * NPOS * DI;
    u16* gTt    = phiT   + (size_t)BATCH * NPOS * DI;

    prep_kernel<<<dim3(NPOS / 256, BATCH, 3), 256, 0, stream>>>(
        x, w_theta, b_theta, w_phi, b_phi, w_g, b_g, thetaT, phiT, gTt);
    attn_kernel<<<dim3(NPOS / 256, BATCH, NCHUNK), 256, 0, stream>>>(
        thetaT, phiT, gTt, Ypart, Lpart);
    merge_kernel<<<dim3((BATCH * NPOS) / 64), 256, 0, stream>>>(
        Ypart, Lpart, x, w_out, b_out, gamma, beta, mean, var, (float*)d_out);
}